// Round 1
// baseline (105.067 us; speedup 1.0000x reference)
//
#include <hip/hip_runtime.h>
#include <cstdint>

namespace {
constexpr int T = 1024;
constexpr int B = 8;
constexpr int D = 512;
constexpr int W = 32;
constexpr int M = T * B; // 8192 rows (t*B+b)
}

// Kernel 1: s[m] = sum_d tanh( sum_e X[m,e] * Wm[e,d] ) * proj[d]
// 256 blocks x 256 threads. Block tile: 32 rows x 512 cols, K streamed in
// 32-wide tiles through LDS. Wave rg owns 8 rows; lane cg owns cols
// {4cg..4cg+3} U {256+4cg..256+4cg+3} (two contiguous-per-wave b128 reads).
__global__ __launch_bounds__(256) void scores_kernel(
    const float* __restrict__ X, const float* __restrict__ Wm,
    const float* __restrict__ proj, float* __restrict__ s_out)
{
    __shared__ float Ws[32][D];
    const int tid  = threadIdx.x;
    const int rg   = tid >> 6;   // wave id 0..3
    const int cg   = tid & 63;   // lane
    const int row0 = blockIdx.x * 32 + rg * 8;

    float acc[8][8];
#pragma unroll
    for (int i = 0; i < 8; ++i)
#pragma unroll
        for (int j = 0; j < 8; ++j) acc[i][j] = 0.f;

    const float4* X4 = reinterpret_cast<const float4*>(X);
    const float4* W4 = reinterpret_cast<const float4*>(Wm);

    for (int kt = 0; kt < D / 32; ++kt) {
        __syncthreads();
        // stage W[kt*32 .. kt*32+32)[0..512) -> Ws (coalesced float4)
#pragma unroll
        for (int it = 0; it < 16; ++it) {
            const int v     = tid + it * 256;   // 0..4095
            const int e_loc = v >> 7;           // 0..31
            const int c4    = v & 127;          // 0..127
            const float4 w  = W4[(size_t)(kt * 32 + e_loc) * (D / 4) + c4];
            *reinterpret_cast<float4*>(&Ws[e_loc][c4 * 4]) = w;
        }
        __syncthreads();

#pragma unroll
        for (int e4 = 0; e4 < 8; ++e4) {
            const int eg = kt * 32 + e4 * 4;
            float4 xv[8];
#pragma unroll
            for (int i = 0; i < 8; ++i)
                xv[i] = X4[(size_t)(row0 + i) * (D / 4) + (eg >> 2)]; // wave-uniform broadcast

#pragma unroll
            for (int q = 0; q < 4; ++q) {
                const float4 w0 = *reinterpret_cast<const float4*>(&Ws[e4 * 4 + q][cg * 4]);
                const float4 w1 = *reinterpret_cast<const float4*>(&Ws[e4 * 4 + q][256 + cg * 4]);
#pragma unroll
                for (int i = 0; i < 8; ++i) {
                    const float xs = reinterpret_cast<const float*>(&xv[i])[q];
                    acc[i][0] = fmaf(xs, w0.x, acc[i][0]);
                    acc[i][1] = fmaf(xs, w0.y, acc[i][1]);
                    acc[i][2] = fmaf(xs, w0.z, acc[i][2]);
                    acc[i][3] = fmaf(xs, w0.w, acc[i][3]);
                    acc[i][4] = fmaf(xs, w1.x, acc[i][4]);
                    acc[i][5] = fmaf(xs, w1.y, acc[i][5]);
                    acc[i][6] = fmaf(xs, w1.z, acc[i][6]);
                    acc[i][7] = fmaf(xs, w1.w, acc[i][7]);
                }
            }
        }
    }

    // Epilogue: tanh, dot with proj over this lane's 8 columns, wave-reduce.
    float pj[8];
#pragma unroll
    for (int j = 0; j < 4; ++j) pj[j] = proj[cg * 4 + j];
#pragma unroll
    for (int j = 0; j < 4; ++j) pj[4 + j] = proj[256 + cg * 4 + j];

#pragma unroll
    for (int i = 0; i < 8; ++i) {
        float part = 0.f;
#pragma unroll
        for (int j = 0; j < 8; ++j) part += tanhf(acc[i][j]) * pj[j];
#pragma unroll
        for (int off = 32; off > 0; off >>= 1)
            part += __shfl_down(part, off, 64);
        if (cg == 0) s_out[row0 + i] = part;
    }
}

// Kernel 1b: p[t, :] = softmax over the 8 batch entries of s[t, :].
__global__ __launch_bounds__(256) void softmax_b_kernel(
    const float* __restrict__ s, float* __restrict__ p)
{
    const int t = blockIdx.x * 256 + threadIdx.x;
    if (t >= T) return;
    const float4 v0 = reinterpret_cast<const float4*>(s)[t * 2];
    const float4 v1 = reinterpret_cast<const float4*>(s)[t * 2 + 1];
    float vals[8] = {v0.x, v0.y, v0.z, v0.w, v1.x, v1.y, v1.z, v1.w};
    float mx = vals[0];
#pragma unroll
    for (int j = 1; j < 8; ++j) mx = fmaxf(mx, vals[j]);
    float sum = 0.f;
#pragma unroll
    for (int j = 0; j < 8; ++j) { vals[j] = __expf(vals[j] - mx); sum += vals[j]; }
    const float inv = 1.f / sum;
    const float4 o0 = {vals[0] * inv, vals[1] * inv, vals[2] * inv, vals[3] * inv};
    const float4 o1 = {vals[4] * inv, vals[5] * inv, vals[6] * inv, vals[7] * inv};
    reinterpret_cast<float4*>(p)[t * 2]     = o0;
    reinterpret_cast<float4*>(p)[t * 2 + 1] = o1;
}

// Kernel 2: out[i,b,:] = X[i,b,:]              (i <  W)
//           out[i,b,:] = sum_k p[i-W+k,b] * X[i-W+k,b,:]   (i >= W)
// Grid 2048 blocks: b = bid&7 (one batch slice per XCD for L2 locality),
// ig = bid>>3; wave rg handles output row i = ig*4+rg; lane owns 8 floats.
__global__ __launch_bounds__(256) void attend_kernel(
    const float* __restrict__ X, const float* __restrict__ p,
    float* __restrict__ out)
{
    const int bid  = blockIdx.x;
    const int b    = bid & 7;
    const int ig   = bid >> 3;
    const int rg   = threadIdx.x >> 6;
    const int lane = threadIdx.x & 63;
    const int i    = ig * 4 + rg;

    const float4* X4 = reinterpret_cast<const float4*>(X);
    float4* O4       = reinterpret_cast<float4*>(out);
    const size_t obase = (size_t)(i * B + b) * (D / 4) + lane * 2;

    if (i < W) {
        O4[obase]     = X4[obase];
        O4[obase + 1] = X4[obase + 1];
        return;
    }

    float4 a0 = {0.f, 0.f, 0.f, 0.f}, a1 = {0.f, 0.f, 0.f, 0.f};
#pragma unroll 4
    for (int k = 0; k < W; ++k) {
        const int tau  = i - W + k;
        const float pw = p[tau * B + b];
        const size_t rbase = (size_t)(tau * B + b) * (D / 4) + lane * 2;
        const float4 v0 = X4[rbase];
        const float4 v1 = X4[rbase + 1];
        a0.x = fmaf(pw, v0.x, a0.x); a0.y = fmaf(pw, v0.y, a0.y);
        a0.z = fmaf(pw, v0.z, a0.z); a0.w = fmaf(pw, v0.w, a0.w);
        a1.x = fmaf(pw, v1.x, a1.x); a1.y = fmaf(pw, v1.y, a1.y);
        a1.z = fmaf(pw, v1.z, a1.z); a1.w = fmaf(pw, v1.w, a1.w);
    }
    O4[obase]     = a0;
    O4[obase + 1] = a1;
}

extern "C" void kernel_launch(void* const* d_in, const int* in_sizes, int n_in,
                              void* d_out, int out_size, void* d_ws, size_t ws_size,
                              hipStream_t stream)
{
    const float* X    = (const float*)d_in[0];
    const float* Wm   = (const float*)d_in[1];
    const float* proj = (const float*)d_in[2];
    float* out = (float*)d_out;

    float* s_buf = (float*)d_ws;      // M floats (pre-softmax scores)
    float* p_buf = s_buf + M;         // M floats (softmax-over-B weights)

    scores_kernel<<<M / 32, 256, 0, stream>>>(X, Wm, proj, s_buf);
    softmax_b_kernel<<<(T + 255) / 256, 256, 0, stream>>>(s_buf, p_buf);
    attend_kernel<<<(T / 4) * B, 256, 0, stream>>>(X, p_buf, out);
}

// Round 2
// 49.226 us; speedup vs baseline: 2.1344x; 2.1344x over previous
//
#include <hip/hip_runtime.h>
#include <cstdint>

namespace {
constexpr int T = 1024;
constexpr int B = 8;
constexpr int D = 512;
constexpr int W = 32;
constexpr int M = T * B; // 8192 rows (t*B+b)
}

using half8  = __attribute__((ext_vector_type(8))) _Float16;
using f32x16 = __attribute__((ext_vector_type(16))) float;

__device__ __forceinline__ void gload16(const void* g, void* l) {
    __builtin_amdgcn_global_load_lds(
        (const __attribute__((address_space(1))) void*)g,
        (__attribute__((address_space(3))) void*)l, 16, 0, 0);
}

__device__ __forceinline__ float fast_tanh(float x) {
    float e = __expf(2.f * x);
    return 1.f - 2.f / (e + 1.f);
}

// ---- prep: X fp32 -> A_h fp16 row-major [M][D] ----
__global__ __launch_bounds__(256) void prep_a(const float* __restrict__ X,
                                              _Float16* __restrict__ Ah) {
    const int idx = blockIdx.x * 256 + threadIdx.x;       // 0..524287, 8 elems each
    const float4* X4 = reinterpret_cast<const float4*>(X);
    const float4 v0 = X4[idx * 2];
    const float4 v1 = X4[idx * 2 + 1];
    half8 h;
    h[0] = (_Float16)v0.x; h[1] = (_Float16)v0.y; h[2] = (_Float16)v0.z; h[3] = (_Float16)v0.w;
    h[4] = (_Float16)v1.x; h[5] = (_Float16)v1.y; h[6] = (_Float16)v1.z; h[7] = (_Float16)v1.w;
    *reinterpret_cast<half8*>(Ah + (size_t)idx * 8) = h;
}

// ---- prep: W fp32 [e][d] -> Bt fp16 [d][e] (transpose via LDS tile) ----
__global__ __launch_bounds__(256) void prep_b(const float* __restrict__ Wm,
                                              _Float16* __restrict__ Bt) {
    __shared__ float tile[64][65];
    const int bd = blockIdx.x & 7;    // d-tile
    const int be = blockIdx.x >> 3;   // e-tile
    const int t  = threadIdx.x;
    const int r  = t >> 2;            // 0..63
    const int c0 = (t & 3) * 16;      // 0,16,32,48
    const float* src = Wm + (size_t)(be * 64 + r) * 512 + bd * 64 + c0;
#pragma unroll
    for (int j = 0; j < 16; j += 4) {
        const float4 v = *reinterpret_cast<const float4*>(src + j);
        tile[r][c0 + j]     = v.x;
        tile[r][c0 + j + 1] = v.y;
        tile[r][c0 + j + 2] = v.z;
        tile[r][c0 + j + 3] = v.w;
    }
    __syncthreads();
    const int dd = t >> 2;            // output row within d-tile
    const int e0 = (t & 3) * 16;      // e offset
    half8 h0, h1;
#pragma unroll
    for (int j = 0; j < 8; ++j)  h0[j] = (_Float16)tile[e0 + j][dd];
#pragma unroll
    for (int j = 0; j < 8; ++j)  h1[j] = (_Float16)tile[e0 + 8 + j][dd];
    _Float16* dst = Bt + (size_t)(bd * 64 + dd) * 512 + be * 64 + e0;
    *reinterpret_cast<half8*>(dst)     = h0;
    *reinterpret_cast<half8*>(dst + 8) = h1;
}

// ---- fused GEMM + tanh + proj-dot: writes spart[8][M] (64-col partials) ----
// 256 blocks x 256 threads. Block tile 128x128, 4 waves 2x2, wave 64x64 of
// 32x32x16 f16 MFMA. BK=64, double-buffered global_load_lds(16B) staging with
// pre-swizzled source (chunk ^= row&7), swizzled ds_read_b128 (2-way, free).
__global__ __launch_bounds__(256) void gemm_scores(
    const _Float16* __restrict__ Ah, const _Float16* __restrict__ Bt,
    const float* __restrict__ proj, float* __restrict__ spart)
{
    __shared__ char lds_buf[65536]; // [2 bufs][A 16K | B 16K]

    const int tid  = threadIdx.x;
    const int lane = tid & 63;
    const int wv   = tid >> 6;      // wave 0..3
    const int wm   = wv >> 1;       // 0..1 (m half)
    const int wn   = wv & 1;        // 0..1 (n half)
    const int hi   = lane >> 5;     // k-group half
    const int l31  = lane & 31;
    const int l7   = lane & 7;

    // XCD-aware swizzle: xcd gets contiguous wgids; mb fastest-ish for A reuse
    const int bid  = blockIdx.x;
    const int wgid = (bid & 7) * 32 + (bid >> 3);
    const int mb   = wgid >> 2;     // 0..63
    const int nb   = wgid & 3;      // 0..3
    const int m0   = mb * 128;
    const int n0   = nb * 128;

    const int wbase = __builtin_amdgcn_readfirstlane(tid & ~63);

    f32x16 acc00 = {}, acc01 = {}, acc10 = {}, acc11 = {};

    auto stage = [&](int bufi, int kt) {
        char* abase = lds_buf + bufi * 32768;
        char* bbase = abase + 16384;
        const int kbase = kt * 64;
#pragma unroll
        for (int i = 0; i < 4; ++i) {
            const int c   = i * 256 + tid;      // chunk 0..1023
            const int row = c >> 3;             // 0..127
            const int ch  = c & 7;              // 16B chunk in row
            const int koff = kbase + ((ch ^ (row & 7)) << 3); // halfwords
            gload16(Ah + (size_t)(m0 + row) * 512 + koff,
                    abase + (size_t)(i * 256 + wbase) * 16);
            gload16(Bt + (size_t)(n0 + row) * 512 + koff,
                    bbase + (size_t)(i * 256 + wbase) * 16);
        }
    };

    stage(0, 0);
    asm volatile("s_waitcnt vmcnt(0)" ::: "memory");
    __syncthreads();

    int cur = 0;
    const int rowA0 = wm * 64 + l31;        // A-tile rows (row&7 == l7)
    const int rowA1 = rowA0 + 32;
    const int colB0 = wn * 64 + l31;        // B-tile cols
    const int colB1 = colB0 + 32;

    for (int kt = 0; kt < 8; ++kt) {
        if (kt < 7) stage(cur ^ 1, kt + 1);

        const char* Ab = lds_buf + cur * 32768;
        const char* Bb = Ab + 16384;

        half8 af0[4], af1[4], bf0[4], bf1[4];
#pragma unroll
        for (int s = 0; s < 4; ++s) {
            const int ch = ((2 * s + hi) ^ l7) << 4; // byte offset of chunk
            af0[s] = *reinterpret_cast<const half8*>(Ab + rowA0 * 128 + ch);
            af1[s] = *reinterpret_cast<const half8*>(Ab + rowA1 * 128 + ch);
            bf0[s] = *reinterpret_cast<const half8*>(Bb + colB0 * 128 + ch);
            bf1[s] = *reinterpret_cast<const half8*>(Bb + colB1 * 128 + ch);
        }
        __builtin_amdgcn_s_setprio(1);
#pragma unroll
        for (int s = 0; s < 4; ++s) {
            acc00 = __builtin_amdgcn_mfma_f32_32x32x16_f16(af0[s], bf0[s], acc00, 0, 0, 0);
            acc01 = __builtin_amdgcn_mfma_f32_32x32x16_f16(af0[s], bf1[s], acc01, 0, 0, 0);
            acc10 = __builtin_amdgcn_mfma_f32_32x32x16_f16(af1[s], bf0[s], acc10, 0, 0, 0);
            acc11 = __builtin_amdgcn_mfma_f32_32x32x16_f16(af1[s], bf1[s], acc11, 0, 0, 0);
        }
        __builtin_amdgcn_s_setprio(0);

        if (kt < 7) asm volatile("s_waitcnt vmcnt(0)" ::: "memory");
        __syncthreads();
        cur ^= 1;
    }

    // Epilogue: s_partial[row] = sum_cols tanh(c)*proj[col] over this wave's
    // 64 cols; C/D layout (32x32): col = lane&31, row = (reg&3)+8*(reg>>2)+4*hi.
    const float pj0 = proj[n0 + wn * 64 + l31];
    const float pj1 = proj[n0 + wn * 64 + 32 + l31];
    float* sp = spart + (size_t)(nb * 2 + wn) * M;

#pragma unroll
    for (int reg = 0; reg < 16; ++reg) {
        float v0 = fast_tanh(acc00[reg]) * pj0 + fast_tanh(acc01[reg]) * pj1;
        float v1 = fast_tanh(acc10[reg]) * pj0 + fast_tanh(acc11[reg]) * pj1;
#pragma unroll
        for (int msk = 1; msk < 32; msk <<= 1) {
            v0 += __shfl_xor(v0, msk, 64);
            v1 += __shfl_xor(v1, msk, 64);
        }
        if (l31 == 0) {
            const int rl = (reg & 3) + 8 * (reg >> 2) + 4 * hi;
            const int m  = m0 + wm * 64 + rl;
            sp[m]      = v0;
            sp[m + 32] = v1;
        }
    }
}

// ---- reduce the 8 col-group partials + softmax over batch ----
__global__ __launch_bounds__(256) void reduce_softmax(
    const float* __restrict__ spart, float* __restrict__ p)
{
    const int t = blockIdx.x * 256 + threadIdx.x;
    if (t >= T) return;
    float s[8] = {0.f, 0.f, 0.f, 0.f, 0.f, 0.f, 0.f, 0.f};
#pragma unroll
    for (int g = 0; g < 8; ++g) {
        const float4* q = reinterpret_cast<const float4*>(spart + (size_t)g * M + t * 8);
        const float4 a = q[0], b = q[1];
        s[0] += a.x; s[1] += a.y; s[2] += a.z; s[3] += a.w;
        s[4] += b.x; s[5] += b.y; s[6] += b.z; s[7] += b.w;
    }
    float mx = s[0];
#pragma unroll
    for (int j = 1; j < 8; ++j) mx = fmaxf(mx, s[j]);
    float sum = 0.f;
#pragma unroll
    for (int j = 0; j < 8; ++j) { s[j] = __expf(s[j] - mx); sum += s[j]; }
    const float inv = 1.f / sum;
    const float4 o0 = {s[0] * inv, s[1] * inv, s[2] * inv, s[3] * inv};
    const float4 o1 = {s[4] * inv, s[5] * inv, s[6] * inv, s[7] * inv};
    reinterpret_cast<float4*>(p)[t * 2]     = o0;
    reinterpret_cast<float4*>(p)[t * 2 + 1] = o1;
}

// ---- attend: out[i,b,:] = X[i,b,:] (i<W) else sum_k p[i-W+k,b]*X[i-W+k,b,:] ----
__global__ __launch_bounds__(256) void attend_kernel(
    const float* __restrict__ X, const float* __restrict__ p,
    float* __restrict__ out)
{
    const int bid  = blockIdx.x;
    const int b    = bid & 7;
    const int ig   = bid >> 3;
    const int rg   = threadIdx.x >> 6;
    const int lane = threadIdx.x & 63;
    const int i    = ig * 4 + rg;

    const float4* X4 = reinterpret_cast<const float4*>(X);
    float4* O4       = reinterpret_cast<float4*>(out);
    const size_t obase = (size_t)(i * B + b) * (D / 4) + lane * 2;

    if (i < W) {
        O4[obase]     = X4[obase];
        O4[obase + 1] = X4[obase + 1];
        return;
    }

    float4 a0 = {0.f, 0.f, 0.f, 0.f}, a1 = {0.f, 0.f, 0.f, 0.f};
#pragma unroll 4
    for (int k = 0; k < W; ++k) {
        const int tau  = i - W + k;
        const float pw = p[tau * B + b];
        const size_t rbase = (size_t)(tau * B + b) * (D / 4) + lane * 2;
        const float4 v0 = X4[rbase];
        const float4 v1 = X4[rbase + 1];
        a0.x = fmaf(pw, v0.x, a0.x); a0.y = fmaf(pw, v0.y, a0.y);
        a0.z = fmaf(pw, v0.z, a0.z); a0.w = fmaf(pw, v0.w, a0.w);
        a1.x = fmaf(pw, v1.x, a1.x); a1.y = fmaf(pw, v1.y, a1.y);
        a1.z = fmaf(pw, v1.z, a1.z); a1.w = fmaf(pw, v1.w, a1.w);
    }
    O4[obase]     = a0;
    O4[obase + 1] = a1;
}

extern "C" void kernel_launch(void* const* d_in, const int* in_sizes, int n_in,
                              void* d_out, int out_size, void* d_ws, size_t ws_size,
                              hipStream_t stream)
{
    const float* X    = (const float*)d_in[0];
    const float* Wm   = (const float*)d_in[1];
    const float* proj = (const float*)d_in[2];
    float* out = (float*)d_out;

    _Float16* Ah   = (_Float16*)d_ws;          // 8 MB: [M][D] fp16
    _Float16* Bt   = Ah + (size_t)M * D;       // 0.5 MB: [D][D] fp16 (transposed W)
    float*    sprt = (float*)(Bt + (size_t)D * D); // 8*M floats
    float*    p    = sprt + 8 * M;             // M floats

    prep_a<<<(M * D / 8) / 256, 256, 0, stream>>>(X, Ah);
    prep_b<<<64, 256, 0, stream>>>(Wm, Bt);
    gemm_scores<<<256, 256, 0, stream>>>(Ah, Bt, proj, sprt);
    reduce_softmax<<<(T + 255) / 256, 256, 0, stream>>>(sprt, p);
    attend_kernel<<<(T / 4) * B, 256, 0, stream>>>(X, p, out);
}